// Round 19
// baseline (108.589 us; speedup 1.0000x reference)
//
#include <hip/hip_runtime.h>
#include <math.h>

#define N_TOK 65536
#define DIM   512
#define HID   102
#define KTOK  64
#define NTILE 4096          // 16-token tiles
#define LN_EPS 1e-5f

typedef __attribute__((ext_vector_type(8))) short short8;
typedef __attribute__((ext_vector_type(4))) float f32x4;

// ws layout (float offsets)
#define WS_LOGITS 0u
#define WS_PART   4194304u                 // 128*64*512
#define WS_PM     (WS_PART + 4194304u)     // 4096*64
#define WS_PS     (WS_PM + 262144u)        // 4096*64
#define WS_W1F    (WS_PS + 262144u)        // 65536 ushort (chunk-packed frags, gamma-folded)
#define WS_W2F    (WS_W1F + 32768u)        // 8192 ushort (packed frags)
#define WS_UB     (WS_W2F + 4096u)         // 128: sum(beta*W1)+b1
#define WS_VV     (WS_UB + 128u)           // 128: sum(gamma*W1)
#define WS_SMAX   (WS_VV + 128u)
#define WS_SINV   (WS_SMAX + 64u)

__device__ __forceinline__ unsigned short f2bf(float f) {
    unsigned int u = __float_as_uint(f);
    unsigned int r = (u + 0x7fffu + ((u >> 16) & 1u)) >> 16;
    return (unsigned short)r;
}
__device__ __forceinline__ float bf2f(unsigned short h) {
    return __uint_as_float(((unsigned int)h) << 16);
}

__device__ __forceinline__ void gload_lds16(const void* g, void* l) {
    __builtin_amdgcn_global_load_lds(
        (const __attribute__((address_space(1))) unsigned int*)g,
        (__attribute__((address_space(3))) unsigned int*)l, 16, 0, 0);
}

// LDS-only barrier (does NOT drain vmcnt -> global prefetches stay in flight)
__device__ __forceinline__ void bar_lds() {
    asm volatile("s_waitcnt lgkmcnt(0)" ::: "memory");
    __builtin_amdgcn_s_barrier();
    __builtin_amdgcn_sched_barrier(0);
}

// ---------------- prep: weights packed in MFMA-fragment order ----------------
__global__ __launch_bounds__(256) void prep_k(const float* __restrict__ W1,
                                              const float* __restrict__ gamma,
                                              const float* __restrict__ W2,
                                              unsigned short* __restrict__ W1f,
                                              unsigned short* __restrict__ W2f) {
    const int idx = blockIdx.x * 256 + threadIdx.x;   // 0..65535
    {
        const int e = idx & 7, lane = (idx >> 3) & 63;
        const int jj = (idx >> 9) & 7, kc = (idx >> 12) & 15;
        const int j = jj * 16 + (lane & 15);
        const int d = kc * 32 + (lane >> 4) * 8 + e;
        W1f[idx] = (j < HID) ? f2bf(gamma[d] * W1[d * HID + j]) : (unsigned short)0;
    }
    if (idx < 8192) {
        const int e = idx & 7, lane = (idx >> 3) & 63;
        const int kc = (idx >> 9) & 3, N = (idx >> 11) & 3;
        const int j = kc * 32 + (lane >> 4) * 8 + e;
        const int k = N * 16 + (lane & 15);
        W2f[idx] = (j < HID) ? f2bf(W2[j * KTOK + k]) : (unsigned short)0;
    }
}

// ---------------- prep2: ub[j]=sum_d beta*W1 + b1, vv[j]=sum_d gamma*W1 ----------------
__global__ __launch_bounds__(512) void prep2_k(const float* __restrict__ W1,
                                               const float* __restrict__ b1,
                                               const float* __restrict__ gamma,
                                               const float* __restrict__ beta,
                                               float* __restrict__ ub,
                                               float* __restrict__ vv) {
    __shared__ float su[4][128], sv[4][128];
    const int t = threadIdx.x;
    const int j = t & 127, q = t >> 7;
    float u = 0.0f, v = 0.0f;
    if (j < HID) {
        #pragma unroll 8
        for (int d = q * 128; d < q * 128 + 128; ++d) {
            const float wv = W1[d * HID + j];
            u = fmaf(beta[d], wv, u);
            v = fmaf(gamma[d], wv, v);
        }
    }
    su[q][j] = u; sv[q][j] = v;
    __syncthreads();
    if (q == 0) {
        ub[j] = su[0][j] + su[1][j] + su[2][j] + su[3][j] +
                ((j < HID) ? b1[j] : 0.0f);
        vv[j] = sv[0][j] + sv[1][j] + sv[2][j] + sv[3][j];
    }
}

// ------- scorer: 128 tokens/block (8 waves), fused loop, BK=64 -> 8 K-steps;
//         3x16KB W1f buffers (stage AFTER barrier), x depth-2 (3x4 slots) -------
__global__ __launch_bounds__(512) void scorer_k(const float* __restrict__ x,
                                                const unsigned short* __restrict__ W1f,
                                                const unsigned short* __restrict__ W2f,
                                                const float* __restrict__ ub,
                                                const float* __restrict__ vv,
                                                const float* __restrict__ b2,
                                                const float* __restrict__ scale,
                                                float* __restrict__ logits,
                                                float* __restrict__ pm,
                                                float* __restrict__ psum) {
    __shared__ char smem[3 * 16384];    // 3 B-buffers (16KB); post-fc1 h[8][4096] alias
    const int tid = threadIdx.x;
    const int lane = tid & 63;
    const int w = tid >> 6;             // wave 0..7
    const int l15 = lane & 15;
    const int hi = lane >> 4;
    const int tile = blockIdx.x * 8 + w;
    const int wt0 = tile * 16;
    char* hb = smem + w * 4096;         // valid only after fc1 + barrier

    const float* xrow = x + (size_t)(wt0 + l15) * DIM + hi * 8;

    // prologue FIFO: x0(4) x1(4) D0(2) D1(2)
    f32x4 xs_[3][4];
    xs_[0][0] = *(const f32x4*)(xrow);
    xs_[0][1] = *(const f32x4*)(xrow + 4);
    xs_[0][2] = *(const f32x4*)(xrow + 32);
    xs_[0][3] = *(const f32x4*)(xrow + 36);
    xs_[1][0] = *(const f32x4*)(xrow + 64);
    xs_[1][1] = *(const f32x4*)(xrow + 68);
    xs_[1][2] = *(const f32x4*)(xrow + 96);
    xs_[1][3] = *(const f32x4*)(xrow + 100);
    gload_lds16(W1f + w * 1024 + lane * 8, smem + w * 2048);
    gload_lds16(W1f + w * 1024 + 512 + lane * 8, smem + w * 2048 + 1024);
    gload_lds16(W1f + 8192 + w * 1024 + lane * 8, smem + 16384 + w * 2048);
    gload_lds16(W1f + 8192 + w * 1024 + 512 + lane * 8, smem + 16384 + w * 2048 + 1024);

    // ---- fused loop: 8 K-steps (BK=64); s/ss accumulate from the fragments ----
    f32x4 acc[8] = {};
    float s = 0.0f, ss = 0.0f;
    #pragma unroll
    for (int kc = 0; kc < 8; ++kc) {
        if (kc < 6) {                            // x(kc+2) -> slots[(kc+2)%3]
            xs_[(kc + 2) % 3][0] = *(const f32x4*)(xrow + (kc + 2) * 64);
            xs_[(kc + 2) % 3][1] = *(const f32x4*)(xrow + (kc + 2) * 64 + 4);
            xs_[(kc + 2) % 3][2] = *(const f32x4*)(xrow + (kc + 2) * 64 + 32);
            xs_[(kc + 2) % 3][3] = *(const f32x4*)(xrow + (kc + 2) * 64 + 36);
        }
        // ops newer than D(kc): kc=0 -> 6; kc=1..5 -> 10; kc=6 -> 6; kc=7 -> 0
        if (kc == 0)       asm volatile("s_waitcnt vmcnt(6)" ::: "memory");
        else if (kc <= 5)  asm volatile("s_waitcnt vmcnt(10)" ::: "memory");
        else if (kc == 6)  asm volatile("s_waitcnt vmcnt(6)" ::: "memory");
        else               asm volatile("s_waitcnt vmcnt(0)" ::: "memory");
        __builtin_amdgcn_sched_barrier(0);
        __builtin_amdgcn_s_barrier();            // all waves' D(kc) + x(kc) landed
        if (kc < 6) {                            // stage D(kc+2): buf last read kc-1
            const unsigned short* sn = W1f + (kc + 2) * 8192 + w * 1024 + lane * 8;
            gload_lds16(sn, smem + ((kc + 2) % 3) * 16384 + w * 2048);
            gload_lds16(sn + 512, smem + ((kc + 2) % 3) * 16384 + w * 2048 + 1024);
        }
        #pragma unroll
        for (int ks = 0; ks < 2; ++ks) {
            const f32x4 a = xs_[kc % 3][ks * 2];
            const f32x4 b = xs_[kc % 3][ks * 2 + 1];
            s += a.x + a.y + a.z + a.w + b.x + b.y + b.z + b.w;
            ss += a.x * a.x + a.y * a.y + a.z * a.z + a.w * a.w +
                  b.x * b.x + b.y * b.y + b.z * b.z + b.w * b.w;
            short8 af;
            af[0] = (short)f2bf(a.x); af[1] = (short)f2bf(a.y);
            af[2] = (short)f2bf(a.z); af[3] = (short)f2bf(a.w);
            af[4] = (short)f2bf(b.x); af[5] = (short)f2bf(b.y);
            af[6] = (short)f2bf(b.z); af[7] = (short)f2bf(b.w);
            const char* bb = smem + (kc % 3) * 16384 + ks * 8192 + lane * 16;
            __builtin_amdgcn_s_setprio(1);
            #pragma unroll
            for (int jj = 0; jj < 8; ++jj) {
                const short8 bf = *(const short8*)(bb + jj * 1024);
                acc[jj] = __builtin_amdgcn_mfma_f32_16x16x32_bf16(af, bf, acc[jj], 0, 0, 0);
            }
            __builtin_amdgcn_s_setprio(0);
        }
    }
    __syncthreads();   // all waves done with B buffers -> smem becomes h space

    // ---- LN stats finalize (2-shfl reduce over the 4 lanes sharing a row) ----
    s += __shfl_xor(s, 16); ss += __shfl_xor(ss, 16);
    s += __shfl_xor(s, 32); ss += __shfl_xor(ss, 32);
    const float mu = s * (1.0f / 512.0f);
    const float inv = rsqrtf(ss * (1.0f / 512.0f) - mu * mu + LN_EPS);

    // ---- LN epilogue + bias + GELU -> wave-private LDS (swizzled bf16) ----
    float invr[4], muir[4];
    #pragma unroll
    for (int r = 0; r < 4; ++r) {
        const int tk = 4 * hi + r;
        const float m_ = __shfl(mu, tk);
        const float i_ = __shfl(inv, tk);
        invr[r] = i_;
        muir[r] = m_ * i_;
    }
    #pragma unroll
    for (int jj = 0; jj < 8; ++jj) {
        const int col = jj * 16 + l15;
        const float ubj = ub[col];
        const float vvj = vv[col];
        #pragma unroll
        for (int reg = 0; reg < 4; ++reg) {
            const int t = 4 * hi + reg;
            const float pre = fmaf(invr[reg], acc[jj][reg],
                                   fmaf(-muir[reg], vvj, ubj));
            const float g = 0.5f * pre * (1.0f + erff(pre * 0.70710678118f));
            *(unsigned short*)(hb + t * 256 + ((col * 2) ^ ((t & 7) << 4))) = f2bf(g);
        }
    }
    asm volatile("s_waitcnt lgkmcnt(0)" ::: "memory");
    __builtin_amdgcn_sched_barrier(0);

    // ---- fc2: 16 tokens x 64 k (per-wave, W2f from L2) ----
    f32x4 acc2[4] = {};
    {
        const unsigned short* w2 = W2f + lane * 8;
        #pragma unroll
        for (int kc = 0; kc < 4; ++kc) {
            const short8 a2 = *(const short8*)(hb + l15 * 256 +
                                               ((kc * 64 + hi * 16) ^ ((l15 & 7) << 4)));
            __builtin_amdgcn_s_setprio(1);
            #pragma unroll
            for (int nt = 0; nt < 4; ++nt) {
                const short8 bfr = *(const short8*)(w2 + (size_t)(nt * 4 + kc) * 512);
                acc2[nt] = __builtin_amdgcn_mfma_f32_16x16x32_bf16(a2, bfr, acc2[nt], 0, 0, 0);
            }
            __builtin_amdgcn_s_setprio(0);
        }
    }

    // ---- logits store (16B/lane contiguous) + per-tile softmax partials ----
    const float sc = scale[0];
    #pragma unroll
    for (int nt = 0; nt < 4; ++nt) {
        const int k = nt * 16 + l15;
        const float bb = b2[k];
        f32x4 lv;
        lv.x = (acc2[nt][0] + bb) * sc;
        lv.y = (acc2[nt][1] + bb) * sc;
        lv.z = (acc2[nt][2] + bb) * sc;
        lv.w = (acc2[nt][3] + bb) * sc;
        *(f32x4*)(logits + (size_t)k * N_TOK + wt0 + hi * 4) = lv;
        float m4 = fmaxf(fmaxf(lv.x, lv.y), fmaxf(lv.z, lv.w));
        float s4 = __expf(lv.x - m4) + __expf(lv.y - m4) +
                   __expf(lv.z - m4) + __expf(lv.w - m4);
        #pragma unroll
        for (int o = 16; o <= 32; o <<= 1) {
            const float om = __shfl_xor(m4, o);
            const float os = __shfl_xor(s4, o);
            const float nm = fmaxf(m4, om);
            s4 = s4 * __expf(m4 - nm) + os * __expf(om - nm);
            m4 = nm;
        }
        if (hi == 0) {
            pm[tile * 64 + k] = m4;
            psum[tile * 64 + k] = s4;
        }
    }
}

// ---------------- stats: combine per-tile partials ----------------
__global__ __launch_bounds__(256) void stats_k(const float* __restrict__ pm,
                                               const float* __restrict__ psum,
                                               float* __restrict__ smax,
                                               float* __restrict__ sinv) {
    const int k = blockIdx.x;
    const int tid = threadIdx.x;
    __shared__ float rm[4], rs[4];
    float m = -1e30f, s = 0.0f;
    for (int b = tid; b < NTILE; b += 256) {
        const float pmv = pm[b * 64 + k];
        const float psv = psum[b * 64 + k];
        const float nm = fmaxf(m, pmv);
        s = s * __expf(m - nm) + psv * __expf(pmv - nm);
        m = nm;
    }
    #pragma unroll
    for (int o = 32; o >= 1; o >>= 1) {
        const float om = __shfl_xor(m, o);
        const float os = __shfl_xor(s, o);
        const float nm = fmaxf(m, om);
        s = s * __expf(m - nm) + os * __expf(om - nm);
        m = nm;
    }
    if ((tid & 63) == 0) { rm[tid >> 6] = m; rs[tid >> 6] = s; }
    __syncthreads();
    if (tid == 0) {
        float fm = rm[0], fs = rs[0];
        for (int i = 1; i < 4; ++i) {
            const float nm = fmaxf(fm, rm[i]);
            fs = fs * __expf(fm - nm) + rs[i] * __expf(rm[i] - nm);
            fm = nm;
        }
        smax[k] = fm;
        sinv[k] = 1.0f / fs;
    }
}

// ---------------- agg: MFMA GEMM (R13-proven) ----------------
__global__ __launch_bounds__(512) void agg_k(const float* __restrict__ x,
                                             const float* __restrict__ logits,
                                             const float* __restrict__ smax,
                                             const float* __restrict__ sinv,
                                             float* __restrict__ part) {
    __shared__ char fsm[40960];
    const int tid = threadIdx.x;
    const int lane = tid & 63;
    const int w = tid >> 6;
    const int l15 = lane & 15;
    const int hi = lane >> 4;
    const int dg = blockIdx.y;
    const int tb = blockIdx.x;

    const int sk = tid >> 3;
    const int snp = (tid & 7) * 8;
    const int xd = tid & 127;
    const int xnb = (tid >> 7) * 16;
    const float mk = smax[sk];
    const float ik = sinv[sk];
    const float* lrow = logits + (size_t)sk * N_TOK + tb * 512 + snp;
    const float* xcol = x + (size_t)(tb * 512 + xnb) * DIM + dg * 128 + xd;

    char* pw = fsm + (((sk >> 4) * 2 + (snp >> 5)) * 64 +
                      (sk & 15) + 16 * ((snp & 31) >> 3)) * 16;
    const int xoff0 = (((xd >> 4) * 2 + (xnb >> 5)) * 64 +
                       (xd & 15) + 16 * (((xnb & 31) >> 3) + 0)) * 16;
    const int xoff1 = (((xd >> 4) * 2 + (xnb >> 5)) * 64 +
                       (xd & 15) + 16 * (((xnb & 31) >> 3) + 1)) * 16;

    const int kt = w & 3;
    const int dgr = w >> 2;

    f32x4 acc[4] = {};

    f32x4 pa = *(const f32x4*)(lrow);
    f32x4 pb = *(const f32x4*)(lrow + 4);
    float xl[16];
    #pragma unroll
    for (int i = 0; i < 16; ++i) xl[i] = xcol[(size_t)i * DIM];

    for (int c = 0; c < 8; ++c) {
        {
            short8 pv;
            pv[0] = (short)f2bf(__expf(pa.x - mk) * ik);
            pv[1] = (short)f2bf(__expf(pa.y - mk) * ik);
            pv[2] = (short)f2bf(__expf(pa.z - mk) * ik);
            pv[3] = (short)f2bf(__expf(pa.w - mk) * ik);
            pv[4] = (short)f2bf(__expf(pb.x - mk) * ik);
            pv[5] = (short)f2bf(__expf(pb.y - mk) * ik);
            pv[6] = (short)f2bf(__expf(pb.z - mk) * ik);
            pv[7] = (short)f2bf(__expf(pb.w - mk) * ik);
            *(short8*)pw = pv;
        }
        {
            short8 h0, l0, h1, l1;
            #pragma unroll
            for (int e = 0; e < 8; ++e) {
                const float v = xl[e];
                const unsigned short hb16 = f2bf(v);
                h0[e] = (short)hb16;
                l0[e] = (short)f2bf(v - bf2f(hb16));
            }
            #pragma unroll
            for (int e = 0; e < 8; ++e) {
                const float v = xl[8 + e];
                const unsigned short hb16 = f2bf(v);
                h1[e] = (short)hb16;
                l1[e] = (short)f2bf(v - bf2f(hb16));
            }
            *(short8*)(fsm + 8192 + xoff0) = h0;
            *(short8*)(fsm + 24576 + xoff0) = l0;
            *(short8*)(fsm + 8192 + xoff1) = h1;
            *(short8*)(fsm + 24576 + xoff1) = l1;
        }
        f32x4 pa_n, pb_n;
        float xln[16];
        if (c < 7) {
            pa_n = *(const f32x4*)(lrow + (c + 1) * 64);
            pb_n = *(const f32x4*)(lrow + (c + 1) * 64 + 4);
            #pragma unroll
            for (int i = 0; i < 16; ++i)
                xln[i] = xcol[(size_t)((c + 1) * 64 + i) * DIM];
        }
        bar_lds();

        __builtin_amdgcn_s_setprio(1);
        #pragma unroll
        for (int ns = 0; ns < 2; ++ns) {
            const short8 af =
                *(const short8*)(fsm + ((kt * 2 + ns) * 64 + lane) * 16);
            #pragma unroll
            for (int dt = 0; dt < 4; ++dt) {
                const int dti = dgr * 4 + dt;
                const short8 bh = *(const short8*)(fsm + 8192 +
                                                   ((dti * 2 + ns) * 64 + lane) * 16);
                const short8 bl = *(const short8*)(fsm + 24576 +
                                                   ((dti * 2 + ns) * 64 + lane) * 16);
                acc[dt] = __builtin_amdgcn_mfma_f32_16x16x32_bf16(af, bh, acc[dt], 0, 0, 0);
                acc[dt] = __builtin_amdgcn_mfma_f32_16x16x32_bf16(af, bl, acc[dt], 0, 0, 0);
            }
        }
        __builtin_amdgcn_s_setprio(0);
        bar_lds();

        pa = pa_n; pb = pb_n;
        #pragma unroll
        for (int i = 0; i < 16; ++i) xl[i] = xln[i];
    }

    #pragma unroll
    for (int dt = 0; dt < 4; ++dt) {
        const int dcol = dg * 128 + (dgr * 4 + dt) * 16 + l15;
        #pragma unroll
        for (int reg = 0; reg < 4; ++reg) {
            const int k = kt * 16 + 4 * hi + reg;
            part[((size_t)tb * 64 + k) * 512 + dcol] = acc[dt][reg];
        }
    }
}

// ---------------- reduce: out[k][d] = sum_tb part[tb][k][d] ----------------
__global__ __launch_bounds__(256) void reduce_k(const float* __restrict__ part,
                                                float* __restrict__ out) {
    const int idx = blockIdx.x * 256 + threadIdx.x;  // 0..32767
    const int k = idx >> 9, d = idx & 511;
    float s = 0.0f;
    for (int tb = 0; tb < 128; ++tb) s += part[((size_t)tb * 64 + k) * 512 + d];
    out[idx] = s;
}

extern "C" void kernel_launch(void* const* d_in, const int* in_sizes, int n_in,
                              void* d_out, int out_size, void* d_ws, size_t ws_size,
                              hipStream_t stream) {
    const float* x     = (const float*)d_in[0];
    const float* gamma = (const float*)d_in[1];
    const float* beta  = (const float*)d_in[2];
    const float* W1    = (const float*)d_in[3];
    const float* b1    = (const float*)d_in[4];
    const float* W2    = (const float*)d_in[5];
    const float* b2    = (const float*)d_in[6];
    const float* scale = (const float*)d_in[7];
    float* out = (float*)d_out;
    float* ws  = (float*)d_ws;

    float* logits = ws + WS_LOGITS;
    float* part   = ws + WS_PART;
    float* pm     = ws + WS_PM;
    float* psum   = ws + WS_PS;
    unsigned short* W1f = (unsigned short*)(ws + WS_W1F);
    unsigned short* W2f = (unsigned short*)(ws + WS_W2F);
    float* ubv  = ws + WS_UB;
    float* vvv  = ws + WS_VV;
    float* smax = ws + WS_SMAX;
    float* sinv = ws + WS_SINV;

    hipLaunchKernelGGL(prep_k, dim3(256), dim3(256), 0, stream,
                       W1, gamma, W2, W1f, W2f);
    hipLaunchKernelGGL(prep2_k, dim3(1), dim3(512), 0, stream,
                       W1, b1, gamma, beta, ubv, vvv);
    hipLaunchKernelGGL(scorer_k, dim3(NTILE / 8), dim3(512), 0, stream,
                       x, W1f, W2f, ubv, vvv, b2, scale, logits, pm, psum);
    hipLaunchKernelGGL(stats_k, dim3(KTOK), dim3(256), 0, stream,
                       pm, psum, smax, sinv);
    hipLaunchKernelGGL(agg_k, dim3(128, 4), dim3(512), 0, stream,
                       x, logits, smax, sinv, part);
    hipLaunchKernelGGL(reduce_k, dim3(128), dim3(256), 0, stream,
                       part, out);
}

// Round 20
// 104.734 us; speedup vs baseline: 1.0368x; 1.0368x over previous
//
#include <hip/hip_runtime.h>
#include <math.h>

#define N_TOK 65536
#define DIM   512
#define HID   102
#define KTOK  64
#define NTILE 4096          // 16-token tiles
#define LN_EPS 1e-5f

typedef __attribute__((ext_vector_type(8))) short short8;
typedef __attribute__((ext_vector_type(4))) float f32x4;

// ws layout (float offsets)
#define WS_LOGITS 0u
#define WS_PART   4194304u                 // 128*64*512
#define WS_PM     (WS_PART + 4194304u)     // 4096*64
#define WS_PS     (WS_PM + 262144u)        // 4096*64
#define WS_W1F    (WS_PS + 262144u)        // 65536 ushort (chunk-packed frags, gamma-folded)
#define WS_W2F    (WS_W1F + 32768u)        // 8192 ushort (packed frags)
#define WS_UB     (WS_W2F + 4096u)         // 128: sum(beta*W1)+b1
#define WS_VV     (WS_UB + 128u)           // 128: sum(gamma*W1)
#define WS_SMAX   (WS_VV + 128u)
#define WS_SINV   (WS_SMAX + 64u)

__device__ __forceinline__ unsigned short f2bf(float f) {
    unsigned int u = __float_as_uint(f);
    unsigned int r = (u + 0x7fffu + ((u >> 16) & 1u)) >> 16;
    return (unsigned short)r;
}
__device__ __forceinline__ float bf2f(unsigned short h) {
    return __uint_as_float(((unsigned int)h) << 16);
}

__device__ __forceinline__ void gload_lds16(const void* g, void* l) {
    __builtin_amdgcn_global_load_lds(
        (const __attribute__((address_space(1))) unsigned int*)g,
        (__attribute__((address_space(3))) unsigned int*)l, 16, 0, 0);
}

// LDS-only barrier (does NOT drain vmcnt -> global prefetches stay in flight)
__device__ __forceinline__ void bar_lds() {
    asm volatile("s_waitcnt lgkmcnt(0)" ::: "memory");
    __builtin_amdgcn_s_barrier();
    __builtin_amdgcn_sched_barrier(0);
}

// ---------------- prep: weights packed in MFMA-fragment order ----------------
__global__ __launch_bounds__(256) void prep_k(const float* __restrict__ W1,
                                              const float* __restrict__ gamma,
                                              const float* __restrict__ W2,
                                              unsigned short* __restrict__ W1f,
                                              unsigned short* __restrict__ W2f) {
    const int idx = blockIdx.x * 256 + threadIdx.x;   // 0..65535
    {
        const int e = idx & 7, lane = (idx >> 3) & 63;
        const int jj = (idx >> 9) & 7, kc = (idx >> 12) & 15;
        const int j = jj * 16 + (lane & 15);
        const int d = kc * 32 + (lane >> 4) * 8 + e;
        W1f[idx] = (j < HID) ? f2bf(gamma[d] * W1[d * HID + j]) : (unsigned short)0;
    }
    if (idx < 8192) {
        const int e = idx & 7, lane = (idx >> 3) & 63;
        const int kc = (idx >> 9) & 3, N = (idx >> 11) & 3;
        const int j = kc * 32 + (lane >> 4) * 8 + e;
        const int k = N * 16 + (lane & 15);
        W2f[idx] = (j < HID) ? f2bf(W2[j * KTOK + k]) : (unsigned short)0;
    }
}

// ---------------- prep2: ub[j]=sum_d beta*W1 + b1, vv[j]=sum_d gamma*W1 ----------------
__global__ __launch_bounds__(512) void prep2_k(const float* __restrict__ W1,
                                               const float* __restrict__ b1,
                                               const float* __restrict__ gamma,
                                               const float* __restrict__ beta,
                                               float* __restrict__ ub,
                                               float* __restrict__ vv) {
    __shared__ float su[4][128], sv[4][128];
    const int t = threadIdx.x;
    const int j = t & 127, q = t >> 7;
    float u = 0.0f, v = 0.0f;
    if (j < HID) {
        #pragma unroll 8
        for (int d = q * 128; d < q * 128 + 128; ++d) {
            const float wv = W1[d * HID + j];
            u = fmaf(beta[d], wv, u);
            v = fmaf(gamma[d], wv, v);
        }
    }
    su[q][j] = u; sv[q][j] = v;
    __syncthreads();
    if (q == 0) {
        ub[j] = su[0][j] + su[1][j] + su[2][j] + su[3][j] +
                ((j < HID) ? b1[j] : 0.0f);
        vv[j] = sv[0][j] + sv[1][j] + sv[2][j] + sv[3][j];
    }
}

// ------- scorer: 64 tokens/block, 4 WAVES (4 independent barrier domains/CU),
//         fused single loop; x depth-2, W1f DMA depth-2, 3x8KB buffers -------
__global__ __launch_bounds__(256) void scorer_k(const float* __restrict__ x,
                                                const unsigned short* __restrict__ W1f,
                                                const unsigned short* __restrict__ W2f,
                                                const float* __restrict__ ub,
                                                const float* __restrict__ vv,
                                                const float* __restrict__ b2,
                                                const float* __restrict__ scale,
                                                float* __restrict__ logits,
                                                float* __restrict__ pm,
                                                float* __restrict__ psum) {
    __shared__ char smem[3 * 8192];     // 3 B-buffers; post-fc1 aliased as h[4][4096]
    const int tid = threadIdx.x;
    const int lane = tid & 63;
    const int w = tid >> 6;             // wave 0..3
    const int l15 = lane & 15;
    const int hi = lane >> 4;
    const int tile = blockIdx.x * 4 + w;
    const int wt0 = tile * 16;
    char* hb = smem + w * 4096;         // valid only after fc1 + barrier

    const float* xrow = x + (size_t)(wt0 + l15) * DIM + hi * 8;

    // prologue FIFO: x0(2) x1(2) D0(2) D1(2)
    f32x4 xva[3], xvb[3];
    xva[0] = *(const f32x4*)(xrow);
    xvb[0] = *(const f32x4*)(xrow + 4);
    xva[1] = *(const f32x4*)(xrow + 32);
    xvb[1] = *(const f32x4*)(xrow + 36);
    gload_lds16(W1f + w * 1024 + lane * 8, smem + w * 2048);
    gload_lds16(W1f + w * 1024 + 512 + lane * 8, smem + w * 2048 + 1024);
    gload_lds16(W1f + 4096 + w * 1024 + lane * 8, smem + 8192 + w * 2048);
    gload_lds16(W1f + 4096 + w * 1024 + 512 + lane * 8, smem + 8192 + w * 2048 + 1024);

    // ---- fused loop: 16 K-steps; s/ss accumulate from the same fragments ----
    f32x4 acc[8] = {};
    float s = 0.0f, ss = 0.0f;
    #pragma unroll
    for (int kc = 0; kc < 16; ++kc) {
        if (kc < 14) {                           // issue group kc+2: x(2) then DMA(2)
            xva[(kc + 2) % 3] = *(const f32x4*)(xrow + (kc + 2) * 32);
            xvb[(kc + 2) % 3] = *(const f32x4*)(xrow + (kc + 2) * 32 + 4);
            const unsigned short* sn = W1f + (kc + 2) * 4096 + w * 1024 + lane * 8;
            gload_lds16(sn, smem + ((kc + 2) % 3) * 8192 + w * 2048);
            gload_lds16(sn + 512, smem + ((kc + 2) % 3) * 8192 + w * 2048 + 1024);
        }
        // ops newer than D(kc): kc=0 -> 6; kc=1..13 -> 8; kc=14 -> 4; kc=15 -> 0
        if (kc == 0)       asm volatile("s_waitcnt vmcnt(6)" ::: "memory");
        else if (kc <= 13) asm volatile("s_waitcnt vmcnt(8)" ::: "memory");
        else if (kc == 14) asm volatile("s_waitcnt vmcnt(4)" ::: "memory");
        else               asm volatile("s_waitcnt vmcnt(0)" ::: "memory");
        __builtin_amdgcn_sched_barrier(0);
        __builtin_amdgcn_s_barrier();            // all 4 waves' D(kc) landed
        const f32x4 a = xva[kc % 3];
        const f32x4 b = xvb[kc % 3];
        s += a.x + a.y + a.z + a.w + b.x + b.y + b.z + b.w;
        ss += a.x * a.x + a.y * a.y + a.z * a.z + a.w * a.w +
              b.x * b.x + b.y * b.y + b.z * b.z + b.w * b.w;
        short8 af;
        af[0] = (short)f2bf(a.x); af[1] = (short)f2bf(a.y);
        af[2] = (short)f2bf(a.z); af[3] = (short)f2bf(a.w);
        af[4] = (short)f2bf(b.x); af[5] = (short)f2bf(b.y);
        af[6] = (short)f2bf(b.z); af[7] = (short)f2bf(b.w);
        const char* bb = smem + (kc % 3) * 8192 + lane * 16;
        __builtin_amdgcn_s_setprio(1);
        #pragma unroll
        for (int jj = 0; jj < 8; ++jj) {
            const short8 bf = *(const short8*)(bb + jj * 1024);
            acc[jj] = __builtin_amdgcn_mfma_f32_16x16x32_bf16(af, bf, acc[jj], 0, 0, 0);
        }
        __builtin_amdgcn_s_setprio(0);
    }
    __syncthreads();   // all waves done with B buffers -> smem becomes h space

    // ---- LN stats finalize (2-shfl reduce over the 4 lanes sharing a row) ----
    s += __shfl_xor(s, 16); ss += __shfl_xor(ss, 16);
    s += __shfl_xor(s, 32); ss += __shfl_xor(ss, 32);
    const float mu = s * (1.0f / 512.0f);
    const float inv = rsqrtf(ss * (1.0f / 512.0f) - mu * mu + LN_EPS);

    // ---- LN epilogue + bias + GELU -> wave-private LDS (swizzled bf16) ----
    float invr[4], muir[4];
    #pragma unroll
    for (int r = 0; r < 4; ++r) {
        const int tk = 4 * hi + r;
        const float m_ = __shfl(mu, tk);
        const float i_ = __shfl(inv, tk);
        invr[r] = i_;
        muir[r] = m_ * i_;
    }
    #pragma unroll
    for (int jj = 0; jj < 8; ++jj) {
        const int col = jj * 16 + l15;
        const float ubj = ub[col];
        const float vvj = vv[col];
        #pragma unroll
        for (int reg = 0; reg < 4; ++reg) {
            const int t = 4 * hi + reg;
            const float pre = fmaf(invr[reg], acc[jj][reg],
                                   fmaf(-muir[reg], vvj, ubj));
            const float g = 0.5f * pre * (1.0f + erff(pre * 0.70710678118f));
            *(unsigned short*)(hb + t * 256 + ((col * 2) ^ ((t & 7) << 4))) = f2bf(g);
        }
    }
    asm volatile("s_waitcnt lgkmcnt(0)" ::: "memory");
    __builtin_amdgcn_sched_barrier(0);

    // ---- fc2: 16 tokens x 64 k (per-wave, W2f from L2) ----
    f32x4 acc2[4] = {};
    {
        const unsigned short* w2 = W2f + lane * 8;
        #pragma unroll
        for (int kc = 0; kc < 4; ++kc) {
            const short8 a2 = *(const short8*)(hb + l15 * 256 +
                                               ((kc * 64 + hi * 16) ^ ((l15 & 7) << 4)));
            __builtin_amdgcn_s_setprio(1);
            #pragma unroll
            for (int nt = 0; nt < 4; ++nt) {
                const short8 bfr = *(const short8*)(w2 + (size_t)(nt * 4 + kc) * 512);
                acc2[nt] = __builtin_amdgcn_mfma_f32_16x16x32_bf16(a2, bfr, acc2[nt], 0, 0, 0);
            }
            __builtin_amdgcn_s_setprio(0);
        }
    }

    // ---- logits store (16B/lane contiguous) + per-tile softmax partials ----
    const float sc = scale[0];
    #pragma unroll
    for (int nt = 0; nt < 4; ++nt) {
        const int k = nt * 16 + l15;
        const float bb = b2[k];
        f32x4 lv;
        lv.x = (acc2[nt][0] + bb) * sc;
        lv.y = (acc2[nt][1] + bb) * sc;
        lv.z = (acc2[nt][2] + bb) * sc;
        lv.w = (acc2[nt][3] + bb) * sc;
        *(f32x4*)(logits + (size_t)k * N_TOK + wt0 + hi * 4) = lv;
        float m4 = fmaxf(fmaxf(lv.x, lv.y), fmaxf(lv.z, lv.w));
        float s4 = __expf(lv.x - m4) + __expf(lv.y - m4) +
                   __expf(lv.z - m4) + __expf(lv.w - m4);
        #pragma unroll
        for (int o = 16; o <= 32; o <<= 1) {
            const float om = __shfl_xor(m4, o);
            const float os = __shfl_xor(s4, o);
            const float nm = fmaxf(m4, om);
            s4 = s4 * __expf(m4 - nm) + os * __expf(om - nm);
            m4 = nm;
        }
        if (hi == 0) {
            pm[tile * 64 + k] = m4;
            psum[tile * 64 + k] = s4;
        }
    }
}

// ---------------- stats: combine per-tile partials ----------------
__global__ __launch_bounds__(256) void stats_k(const float* __restrict__ pm,
                                               const float* __restrict__ psum,
                                               float* __restrict__ smax,
                                               float* __restrict__ sinv) {
    const int k = blockIdx.x;
    const int tid = threadIdx.x;
    __shared__ float rm[4], rs[4];
    float m = -1e30f, s = 0.0f;
    for (int b = tid; b < NTILE; b += 256) {
        const float pmv = pm[b * 64 + k];
        const float psv = psum[b * 64 + k];
        const float nm = fmaxf(m, pmv);
        s = s * __expf(m - nm) + psv * __expf(pmv - nm);
        m = nm;
    }
    #pragma unroll
    for (int o = 32; o >= 1; o >>= 1) {
        const float om = __shfl_xor(m, o);
        const float os = __shfl_xor(s, o);
        const float nm = fmaxf(m, om);
        s = s * __expf(m - nm) + os * __expf(om - nm);
        m = nm;
    }
    if ((tid & 63) == 0) { rm[tid >> 6] = m; rs[tid >> 6] = s; }
    __syncthreads();
    if (tid == 0) {
        float fm = rm[0], fs = rs[0];
        for (int i = 1; i < 4; ++i) {
            const float nm = fmaxf(fm, rm[i]);
            fs = fs * __expf(fm - nm) + rs[i] * __expf(rm[i] - nm);
            fm = nm;
        }
        smax[k] = fm;
        sinv[k] = 1.0f / fs;
    }
}

// ---------------- agg: MFMA GEMM (R13-proven) ----------------
__global__ __launch_bounds__(512) void agg_k(const float* __restrict__ x,
                                             const float* __restrict__ logits,
                                             const float* __restrict__ smax,
                                             const float* __restrict__ sinv,
                                             float* __restrict__ part) {
    __shared__ char fsm[40960];
    const int tid = threadIdx.x;
    const int lane = tid & 63;
    const int w = tid >> 6;
    const int l15 = lane & 15;
    const int hi = lane >> 4;
    const int dg = blockIdx.y;
    const int tb = blockIdx.x;

    const int sk = tid >> 3;
    const int snp = (tid & 7) * 8;
    const int xd = tid & 127;
    const int xnb = (tid >> 7) * 16;
    const float mk = smax[sk];
    const float ik = sinv[sk];
    const float* lrow = logits + (size_t)sk * N_TOK + tb * 512 + snp;
    const float* xcol = x + (size_t)(tb * 512 + xnb) * DIM + dg * 128 + xd;

    char* pw = fsm + (((sk >> 4) * 2 + (snp >> 5)) * 64 +
                      (sk & 15) + 16 * ((snp & 31) >> 3)) * 16;
    const int xoff0 = (((xd >> 4) * 2 + (xnb >> 5)) * 64 +
                       (xd & 15) + 16 * (((xnb & 31) >> 3) + 0)) * 16;
    const int xoff1 = (((xd >> 4) * 2 + (xnb >> 5)) * 64 +
                       (xd & 15) + 16 * (((xnb & 31) >> 3) + 1)) * 16;

    const int kt = w & 3;
    const int dgr = w >> 2;

    f32x4 acc[4] = {};

    f32x4 pa = *(const f32x4*)(lrow);
    f32x4 pb = *(const f32x4*)(lrow + 4);
    float xl[16];
    #pragma unroll
    for (int i = 0; i < 16; ++i) xl[i] = xcol[(size_t)i * DIM];

    for (int c = 0; c < 8; ++c) {
        {
            short8 pv;
            pv[0] = (short)f2bf(__expf(pa.x - mk) * ik);
            pv[1] = (short)f2bf(__expf(pa.y - mk) * ik);
            pv[2] = (short)f2bf(__expf(pa.z - mk) * ik);
            pv[3] = (short)f2bf(__expf(pa.w - mk) * ik);
            pv[4] = (short)f2bf(__expf(pb.x - mk) * ik);
            pv[5] = (short)f2bf(__expf(pb.y - mk) * ik);
            pv[6] = (short)f2bf(__expf(pb.z - mk) * ik);
            pv[7] = (short)f2bf(__expf(pb.w - mk) * ik);
            *(short8*)pw = pv;
        }
        {
            short8 h0, l0, h1, l1;
            #pragma unroll
            for (int e = 0; e < 8; ++e) {
                const float v = xl[e];
                const unsigned short hb16 = f2bf(v);
                h0[e] = (short)hb16;
                l0[e] = (short)f2bf(v - bf2f(hb16));
            }
            #pragma unroll
            for (int e = 0; e < 8; ++e) {
                const float v = xl[8 + e];
                const unsigned short hb16 = f2bf(v);
                h1[e] = (short)hb16;
                l1[e] = (short)f2bf(v - bf2f(hb16));
            }
            *(short8*)(fsm + 8192 + xoff0) = h0;
            *(short8*)(fsm + 24576 + xoff0) = l0;
            *(short8*)(fsm + 8192 + xoff1) = h1;
            *(short8*)(fsm + 24576 + xoff1) = l1;
        }
        f32x4 pa_n, pb_n;
        float xln[16];
        if (c < 7) {
            pa_n = *(const f32x4*)(lrow + (c + 1) * 64);
            pb_n = *(const f32x4*)(lrow + (c + 1) * 64 + 4);
            #pragma unroll
            for (int i = 0; i < 16; ++i)
                xln[i] = xcol[(size_t)((c + 1) * 64 + i) * DIM];
        }
        bar_lds();

        __builtin_amdgcn_s_setprio(1);
        #pragma unroll
        for (int ns = 0; ns < 2; ++ns) {
            const short8 af =
                *(const short8*)(fsm + ((kt * 2 + ns) * 64 + lane) * 16);
            #pragma unroll
            for (int dt = 0; dt < 4; ++dt) {
                const int dti = dgr * 4 + dt;
                const short8 bh = *(const short8*)(fsm + 8192 +
                                                   ((dti * 2 + ns) * 64 + lane) * 16);
                const short8 bl = *(const short8*)(fsm + 24576 +
                                                   ((dti * 2 + ns) * 64 + lane) * 16);
                acc[dt] = __builtin_amdgcn_mfma_f32_16x16x32_bf16(af, bh, acc[dt], 0, 0, 0);
                acc[dt] = __builtin_amdgcn_mfma_f32_16x16x32_bf16(af, bl, acc[dt], 0, 0, 0);
            }
        }
        __builtin_amdgcn_s_setprio(0);
        bar_lds();

        pa = pa_n; pb = pb_n;
        #pragma unroll
        for (int i = 0; i < 16; ++i) xl[i] = xln[i];
    }

    #pragma unroll
    for (int dt = 0; dt < 4; ++dt) {
        const int dcol = dg * 128 + (dgr * 4 + dt) * 16 + l15;
        #pragma unroll
        for (int reg = 0; reg < 4; ++reg) {
            const int k = kt * 16 + 4 * hi + reg;
            part[((size_t)tb * 64 + k) * 512 + dcol] = acc[dt][reg];
        }
    }
}

// ---------------- reduce: out[k][d] = sum_tb part[tb][k][d] ----------------
__global__ __launch_bounds__(256) void reduce_k(const float* __restrict__ part,
                                                float* __restrict__ out) {
    const int idx = blockIdx.x * 256 + threadIdx.x;  // 0..32767
    const int k = idx >> 9, d = idx & 511;
    float s = 0.0f;
    for (int tb = 0; tb < 128; ++tb) s += part[((size_t)tb * 64 + k) * 512 + d];
    out[idx] = s;
}

extern "C" void kernel_launch(void* const* d_in, const int* in_sizes, int n_in,
                              void* d_out, int out_size, void* d_ws, size_t ws_size,
                              hipStream_t stream) {
    const float* x     = (const float*)d_in[0];
    const float* gamma = (const float*)d_in[1];
    const float* beta  = (const float*)d_in[2];
    const float* W1    = (const float*)d_in[3];
    const float* b1    = (const float*)d_in[4];
    const float* W2    = (const float*)d_in[5];
    const float* b2    = (const float*)d_in[6];
    const float* scale = (const float*)d_in[7];
    float* out = (float*)d_out;
    float* ws  = (float*)d_ws;

    float* logits = ws + WS_LOGITS;
    float* part   = ws + WS_PART;
    float* pm     = ws + WS_PM;
    float* psum   = ws + WS_PS;
    unsigned short* W1f = (unsigned short*)(ws + WS_W1F);
    unsigned short* W2f = (unsigned short*)(ws + WS_W2F);
    float* ubv  = ws + WS_UB;
    float* vvv  = ws + WS_VV;
    float* smax = ws + WS_SMAX;
    float* sinv = ws + WS_SINV;

    hipLaunchKernelGGL(prep_k, dim3(256), dim3(256), 0, stream,
                       W1, gamma, W2, W1f, W2f);
    hipLaunchKernelGGL(prep2_k, dim3(1), dim3(512), 0, stream,
                       W1, b1, gamma, beta, ubv, vvv);
    hipLaunchKernelGGL(scorer_k, dim3(NTILE / 4), dim3(256), 0, stream,
                       x, W1f, W2f, ubv, vvv, b2, scale, logits, pm, psum);
    hipLaunchKernelGGL(stats_k, dim3(KTOK), dim3(256), 0, stream,
                       pm, psum, smax, sinv);
    hipLaunchKernelGGL(agg_k, dim3(128, 4), dim3(512), 0, stream,
                       x, logits, smax, sinv, part);
    hipLaunchKernelGGL(reduce_k, dim3(128), dim3(256), 0, stream,
                       part, out);
}